// Round 5
// baseline (172.618 us; speedup 1.0000x reference)
//
#include <hip/hip_runtime.h>
#include <hip/hip_bf16.h>

// R10: wave-owns-ROWS mapping (wave w: rows [16w,16w+16), all 512 codes).
// R9 lesson: wave-owns-codes forced per-iteration Z reads from LDS
// (512 KB/block, ~20 us of LDS BW) each behind an lgkmcnt(0) full drain.
// With rows-mapping the wave's Z fragments are 8 VGPRs computed once; E
// streams from g_efrag (global, L2-hot) with compiler-pipelined counted
// vmcnt. Bonus: pass1 row-min never leaves the wave -> thr lives in a
// register (no cross-wave LDS reduce, one less __syncthreads).
// Register budget pinned by waves_per_eu(4,4) = 128 unified; demand ~60.
// Numerics identical to R6-R9 (absmax 0.0): single-product bf16 scores
// (emb ~ U(+-1/512) -> score err std ~6e-5), EPS=1e-3 band, exact fp32
// reference rescore, u64 (dist_bits<<32|idx) atomicMin strict-< tie-break.
// Both passes use identical zf/e/base bits -> pass1 min == pass2 min exactly.
constexpr int NELEM = 8388608;            // 32*64*64*64
constexpr int ROWS  = 64;                 // rows per block
constexpr int NBLK  = 131072 / ROWS;      // 2048
constexpr int ZS    = 68;                 // fp32 z tile stride (dwords)
constexpr float EPS = 1e-3f;              // single-product band (R6-validated)
constexpr int QCAP  = 1024;               // candidate queue (~110 expected)

typedef short bf16x8 __attribute__((ext_vector_type(8)));
typedef float v4f    __attribute__((ext_vector_type(4)));

// Precomputed E fragments, hi-only, scale -2: [ct][kc][lane] -> 8 bf16, 64 KB.
__device__ bf16x8 g_efrag[32][2][64];
// Precomputed ||e||^2 in exact reference quad-accumulator order.
__device__ float  g_en2[512];

__device__ inline bf16x8 cvt_hi8(const float* __restrict__ s, float scale) {
    bf16x8 h;
#pragma unroll
    for (int j = 0; j < 8; ++j) {
        __hip_bfloat16 b = __float2bfloat16(scale * s[j]);
        h[j] = (short)__bfloat16_as_ushort(b);
    }
    return h;
}

// 17 blocks: 0..15 build E fragments (256 entries each), 16 builds en2 + out[0]=0.
__global__ void __launch_bounds__(256) vq_prep(const float* __restrict__ emb,
                                               float* __restrict__ out) {
    const int b = blockIdx.x;
    if (b < 16) {
        const int id   = b * 256 + threadIdx.x;   // (ct,kc,lane), 4096 total
        const int lane = id & 63;
        const int kc   = (id >> 6) & 1;
        const int ct   = id >> 7;
        const float* src = emb + (size_t)(ct * 16 + (lane & 15)) * 64
                               + kc * 32 + (lane >> 4) * 8;
        g_efrag[ct][kc][lane] = cvt_hi8(src, -2.0f);
    } else {
#pragma unroll
        for (int c = 0; c < 2; ++c) {
            const int k = threadIdx.x + c * 256;
            const float4* e4 = (const float4*)(emb + (size_t)k * 64);
            float a = 0.f, bq = 0.f, cc = 0.f, d = 0.f;
#pragma unroll
            for (int i = 0; i < 16; ++i) {
                float4 v = e4[i];
                a += v.x * v.x; bq += v.y * v.y; cc += v.z * v.z; d += v.w * v.w;
            }
            g_en2[k] = (a + bq) + (cc + d);
        }
        if (threadIdx.x == 0) out[0] = 0.f;
    }
}

// Block = 256 threads = 4 waves, 64 rows x 512 codes. Wave w owns rows
// [16w,16w+16). MFMA 16x16x32: A=-2E (m=code), B=Z (n=row), C: col=lane&15
// (row), row-of-C=quad*4+reg (code) [m89 layout, R5-validated].
// Two-pass: pass1 -> per-row min (in-register), pass2 recompute + band scan.
__global__ __launch_bounds__(256) __attribute__((amdgpu_waves_per_eu(4, 4)))
void vq_main(const float* __restrict__ z,
             const float* __restrict__ emb,
             float* __restrict__ out) {
    __shared__ float s_z[ROWS * ZS];          // 17.4 KB fp32 z tile
    __shared__ float s_en2[512];
    __shared__ float s_zn2[ROWS];
    __shared__ unsigned long long s_key[ROWS];
    __shared__ unsigned s_q[QCAP];            // (row<<16)|code
    __shared__ int s_qn;
    __shared__ float s_lpart[4];

    const int tid  = threadIdx.x;
    const int lane = tid & 63;
    const int wid  = __builtin_amdgcn_readfirstlane(tid >> 6);
    const int mcol = lane & 15;
    const int quad = lane >> 4;

    // ---- stage z tile (coalesced), load en2, init queue/keys ----
    {
        const int row = tid >> 2, seg = tid & 3;
        const float4* gp = (const float4*)(z + ((size_t)blockIdx.x * ROWS + row) * 64 + seg * 16);
#pragma unroll
        for (int i = 0; i < 4; ++i)
            *(float4*)&s_z[row * ZS + seg * 16 + i * 4] = gp[i];
    }
    s_en2[tid]       = g_en2[tid];
    s_en2[tid + 256] = g_en2[tid + 256];
    if (tid < ROWS) s_key[tid] = ~0ULL;
    if (tid == 0) s_qn = 0;
    __syncthreads();

    // ---- exact zn2 per row, 4-way parallel with reference arithmetic:
    //      accumulator s sums z[4i+s] sequentially; combine (a+b)+(c+d).
    {
        const int row = tid >> 2, s = tid & 3;
        const float* zr = &s_z[row * ZS];
        float p = 0.f;
#pragma unroll
        for (int i = 0; i < 16; ++i) p += zr[4 * i + s] * zr[4 * i + s];
        p += __shfl_xor(p, 1, 64);   // a+b | c+d (fp add commutative: bit-exact)
        p += __shfl_xor(p, 2, 64);   // (a+b)+(c+d)
        if (s == 0) s_zn2[row] = p;
    }

    // ---- Z fragments for this wave's 16 rows: 8 VGPRs, computed once ----
    const int zrow = wid * 16 + mcol;
    const bf16x8 zf0 = cvt_hi8(&s_z[zrow * ZS +  0 + quad * 8], 1.0f);
    const bf16x8 zf1 = cvt_hi8(&s_z[zrow * ZS + 32 + quad * 8], 1.0f);

    // ---- pass 1: row min over all 512 codes (E streamed from L2) ----
    float lmin = 3.402823466e38f;
#pragma unroll
    for (int ct = 0; ct < 32; ++ct) {
        bf16x8 e0 = g_efrag[ct][0][lane];
        bf16x8 e1 = g_efrag[ct][1][lane];
        v4f a = *(const v4f*)&s_en2[ct * 16 + quad * 4];  // broadcast read
        a = __builtin_amdgcn_mfma_f32_16x16x32_bf16(e0, zf0, a, 0, 0, 0);
        a = __builtin_amdgcn_mfma_f32_16x16x32_bf16(e1, zf1, a, 0, 0, 0);
        lmin = fminf(lmin, fminf(fminf(a.x, a.y), fminf(a.z, a.w)));
    }
    // row min: lanes mcol, mcol+16, +32, +48 hold quad-partials for zrow
    lmin = fminf(lmin, __shfl_xor(lmin, 16, 64));
    lmin = fminf(lmin, __shfl_xor(lmin, 32, 64));
    const float thr = lmin + EPS;     // in-register; no barrier needed

    // ---- pass 2: recompute (identical bits -> deterministic), band scan ----
#pragma unroll
    for (int ct = 0; ct < 32; ++ct) {
        bf16x8 e0 = g_efrag[ct][0][lane];
        bf16x8 e1 = g_efrag[ct][1][lane];
        v4f a = *(const v4f*)&s_en2[ct * 16 + quad * 4];
        a = __builtin_amdgcn_mfma_f32_16x16x32_bf16(e0, zf0, a, 0, 0, 0);
        a = __builtin_amdgcn_mfma_f32_16x16x32_bf16(e1, zf1, a, 0, 0, 0);
        float m4 = fminf(fminf(a.x, a.y), fminf(a.z, a.w));
        if (m4 <= thr) {
#pragma unroll
            for (int r = 0; r < 4; ++r) {
                if (a[r] <= thr) {
                    int slot = atomicAdd(&s_qn, 1);
                    if (slot < QCAP)
                        s_q[slot] = ((unsigned)zrow << 16) |
                                    (unsigned)(ct * 16 + quad * 4 + r);
                }
            }
        }
    }
    __syncthreads();

    // ---- exact reference rescore of candidates (parallel pass) ----
    {
        const int qn = s_qn;
        for (int i = tid; i < qn && i < QCAP; i += 256) {
            const unsigned e = s_q[i];
            const int row = e >> 16, code = e & 0xFFFF;
            const float* zr = &s_z[row * ZS];
            const float* er = emb + (size_t)code * 64;
            float a = 0.f, b = 0.f, c2 = 0.f, d = 0.f;
#pragma unroll
            for (int g = 0; g < 16; ++g) {
                a  += zr[4*g]   * er[4*g];   b += zr[4*g+1] * er[4*g+1];
                c2 += zr[4*g+2] * er[4*g+2]; d += zr[4*g+3] * er[4*g+3];
            }
            float dot  = (a + b) + (c2 + d);
            float dist = (s_zn2[row] + s_en2[code]) - 2.0f * dot;  // reference expr
            unsigned long long key =
                ((unsigned long long)__float_as_uint(dist) << 32) | (unsigned)code;
            atomicMin(&s_key[row], key);
        }
    }
    __syncthreads();

    // ---- epilogue: quantized_st, indices, loss (row = tid>>2, 16 floats) ----
    const int row = tid >> 2, seg = tid & 3;
    const int widx = (int)(unsigned)(s_key[row] & 0x1FFULL);
    const float* er = emb + (size_t)widx * 64 + seg * 16;
    const float* zr = &s_z[row * ZS + seg * 16];
    float* qo = out + 1 + ((size_t)blockIdx.x * ROWS + row) * 64 + seg * 16;
    float lsum = 0.f;
#pragma unroll
    for (int j = 0; j < 16; ++j) {
        float zv = zr[j], ev = er[j];
        float q = zv + (ev - zv);    // reference STE arithmetic
        float df = q - zv; lsum += df * df;
        qo[j] = q;
    }
    if (seg == 0)
        out[1 + NELEM + blockIdx.x * ROWS + row] = (float)widx;

#pragma unroll
    for (int off = 32; off; off >>= 1) lsum += __shfl_down(lsum, off, 64);
    if (lane == 0) s_lpart[wid] = lsum;
    __syncthreads();
    if (tid == 0) {
        float p = (s_lpart[0] + s_lpart[1]) + (s_lpart[2] + s_lpart[3]);
        atomicAdd(out, p * (1.25f / 8388608.0f));   // recon + 0.25*commit
    }
}

extern "C" void kernel_launch(void* const* d_in, const int* in_sizes, int n_in,
                              void* d_out, int out_size, void* d_ws, size_t ws_size,
                              hipStream_t stream) {
    const float* z   = (const float*)d_in[0];
    const float* emb = (const float*)d_in[1];
    float* out = (float*)d_out;

    vq_prep<<<17, 256, 0, stream>>>(emb, out);   // also zeroes out[0]
    vq_main<<<NBLK, 256, 0, stream>>>(z, emb, out);
}

// Round 7
// 144.141 us; speedup vs baseline: 1.1976x; 1.1976x over previous
//
#include <hip/hip_runtime.h>
#include <hip/hip_bf16.h>

// R11 (resubmit; prior round was an infra failure, no signal).
// R10's wave-owns-rows two-pass structure + UNROLL CAP (4) on the two
// 32-iteration MFMA loops.
// R10 lesson: `#pragma unroll` (full) on a 32-iter loop hoisted ALL e-frag
// loads (32ct x 2 x 8 VGPR = 512 regs live) + 32 x 4-reg s_en2 reads ->
// live-range demand >> 128-reg budget -> mass scratch spill (+86 MB HBM).
// R9 avoided it only because inline-asm ds_reads are un-hoistable; R6 because
// its loop was 8 iters. Fix: unroll 4 -> ~8 loads in flight (~64 regs), total
// demand ~100 < 128 budget of waves_per_eu(4,4). Structure unchanged:
// Z frags in 8 VGPRs computed once, thr in-register (no cross-wave reduce).
// Numerics identical to R6-R10 (absmax 0.0): single-product bf16 scores
// (emb ~ U(+-1/512) -> score err std ~6e-5), EPS=1e-3 band, exact fp32
// reference rescore, u64 (dist_bits<<32|idx) atomicMin strict-< tie-break.
// Both passes use identical zf/e/base bits -> pass1 min == pass2 min exactly.
constexpr int NELEM = 8388608;            // 32*64*64*64
constexpr int ROWS  = 64;                 // rows per block
constexpr int NBLK  = 131072 / ROWS;      // 2048
constexpr int ZS    = 68;                 // fp32 z tile stride (dwords)
constexpr float EPS = 1e-3f;              // single-product band (R6-validated)
constexpr int QCAP  = 1024;               // candidate queue (~110 expected)

typedef short bf16x8 __attribute__((ext_vector_type(8)));
typedef float v4f    __attribute__((ext_vector_type(4)));

// Precomputed E fragments, hi-only, scale -2: [ct][kc][lane] -> 8 bf16, 64 KB.
__device__ bf16x8 g_efrag[32][2][64];
// Precomputed ||e||^2 in exact reference quad-accumulator order.
__device__ float  g_en2[512];

__device__ inline bf16x8 cvt_hi8(const float* __restrict__ s, float scale) {
    bf16x8 h;
#pragma unroll
    for (int j = 0; j < 8; ++j) {
        __hip_bfloat16 b = __float2bfloat16(scale * s[j]);
        h[j] = (short)__bfloat16_as_ushort(b);
    }
    return h;
}

// 17 blocks: 0..15 build E fragments (256 entries each), 16 builds en2 + out[0]=0.
__global__ void __launch_bounds__(256) vq_prep(const float* __restrict__ emb,
                                               float* __restrict__ out) {
    const int b = blockIdx.x;
    if (b < 16) {
        const int id   = b * 256 + threadIdx.x;   // (ct,kc,lane), 4096 total
        const int lane = id & 63;
        const int kc   = (id >> 6) & 1;
        const int ct   = id >> 7;
        const float* src = emb + (size_t)(ct * 16 + (lane & 15)) * 64
                               + kc * 32 + (lane >> 4) * 8;
        g_efrag[ct][kc][lane] = cvt_hi8(src, -2.0f);
    } else {
#pragma unroll
        for (int c = 0; c < 2; ++c) {
            const int k = threadIdx.x + c * 256;
            const float4* e4 = (const float4*)(emb + (size_t)k * 64);
            float a = 0.f, bq = 0.f, cc = 0.f, d = 0.f;
#pragma unroll
            for (int i = 0; i < 16; ++i) {
                float4 v = e4[i];
                a += v.x * v.x; bq += v.y * v.y; cc += v.z * v.z; d += v.w * v.w;
            }
            g_en2[k] = (a + bq) + (cc + d);
        }
        if (threadIdx.x == 0) out[0] = 0.f;
    }
}

// Block = 256 threads = 4 waves, 64 rows x 512 codes. Wave w owns rows
// [16w,16w+16). MFMA 16x16x32: A=-2E (m=code), B=Z (n=row), C: col=lane&15
// (row), row-of-C=quad*4+reg (code) [m89 layout, R5-validated].
// Two-pass: pass1 -> per-row min (in-register), pass2 recompute + band scan.
__global__ __launch_bounds__(256) __attribute__((amdgpu_waves_per_eu(4, 4)))
void vq_main(const float* __restrict__ z,
             const float* __restrict__ emb,
             float* __restrict__ out) {
    __shared__ float s_z[ROWS * ZS];          // 17.4 KB fp32 z tile
    __shared__ float s_en2[512];
    __shared__ float s_zn2[ROWS];
    __shared__ unsigned long long s_key[ROWS];
    __shared__ unsigned s_q[QCAP];            // (row<<16)|code
    __shared__ int s_qn;
    __shared__ float s_lpart[4];

    const int tid  = threadIdx.x;
    const int lane = tid & 63;
    const int wid  = __builtin_amdgcn_readfirstlane(tid >> 6);
    const int mcol = lane & 15;
    const int quad = lane >> 4;

    // ---- stage z tile (coalesced), load en2, init queue/keys ----
    {
        const int row = tid >> 2, seg = tid & 3;
        const float4* gp = (const float4*)(z + ((size_t)blockIdx.x * ROWS + row) * 64 + seg * 16);
#pragma unroll
        for (int i = 0; i < 4; ++i)
            *(float4*)&s_z[row * ZS + seg * 16 + i * 4] = gp[i];
    }
    s_en2[tid]       = g_en2[tid];
    s_en2[tid + 256] = g_en2[tid + 256];
    if (tid < ROWS) s_key[tid] = ~0ULL;
    if (tid == 0) s_qn = 0;
    __syncthreads();

    // ---- exact zn2 per row, 4-way parallel with reference arithmetic:
    //      accumulator s sums z[4i+s] sequentially; combine (a+b)+(c+d).
    {
        const int row = tid >> 2, s = tid & 3;
        const float* zr = &s_z[row * ZS];
        float p = 0.f;
#pragma unroll
        for (int i = 0; i < 16; ++i) p += zr[4 * i + s] * zr[4 * i + s];
        p += __shfl_xor(p, 1, 64);   // a+b | c+d (fp add commutative: bit-exact)
        p += __shfl_xor(p, 2, 64);   // (a+b)+(c+d)
        if (s == 0) s_zn2[row] = p;
    }

    // ---- Z fragments for this wave's 16 rows: 8 VGPRs, computed once ----
    const int zrow = wid * 16 + mcol;
    const bf16x8 zf0 = cvt_hi8(&s_z[zrow * ZS +  0 + quad * 8], 1.0f);
    const bf16x8 zf1 = cvt_hi8(&s_z[zrow * ZS + 32 + quad * 8], 1.0f);

    // ---- pass 1: row min over all 512 codes (E streamed from L2) ----
    // unroll 4: ~8 e-loads (64 VGPRs) in flight, demand stays under budget.
    float lmin = 3.402823466e38f;
#pragma unroll 4
    for (int ct = 0; ct < 32; ++ct) {
        bf16x8 e0 = g_efrag[ct][0][lane];
        bf16x8 e1 = g_efrag[ct][1][lane];
        v4f a = *(const v4f*)&s_en2[ct * 16 + quad * 4];  // broadcast read
        a = __builtin_amdgcn_mfma_f32_16x16x32_bf16(e0, zf0, a, 0, 0, 0);
        a = __builtin_amdgcn_mfma_f32_16x16x32_bf16(e1, zf1, a, 0, 0, 0);
        lmin = fminf(lmin, fminf(fminf(a.x, a.y), fminf(a.z, a.w)));
    }
    // row min: lanes mcol, mcol+16, +32, +48 hold quad-partials for zrow
    lmin = fminf(lmin, __shfl_xor(lmin, 16, 64));
    lmin = fminf(lmin, __shfl_xor(lmin, 32, 64));
    const float thr = lmin + EPS;     // in-register; no barrier needed

    // ---- pass 2: recompute (identical bits -> deterministic), band scan ----
#pragma unroll 4
    for (int ct = 0; ct < 32; ++ct) {
        bf16x8 e0 = g_efrag[ct][0][lane];
        bf16x8 e1 = g_efrag[ct][1][lane];
        v4f a = *(const v4f*)&s_en2[ct * 16 + quad * 4];
        a = __builtin_amdgcn_mfma_f32_16x16x32_bf16(e0, zf0, a, 0, 0, 0);
        a = __builtin_amdgcn_mfma_f32_16x16x32_bf16(e1, zf1, a, 0, 0, 0);
        float m4 = fminf(fminf(a.x, a.y), fminf(a.z, a.w));
        if (m4 <= thr) {
#pragma unroll
            for (int r = 0; r < 4; ++r) {
                if (a[r] <= thr) {
                    int slot = atomicAdd(&s_qn, 1);
                    if (slot < QCAP)
                        s_q[slot] = ((unsigned)zrow << 16) |
                                    (unsigned)(ct * 16 + quad * 4 + r);
                }
            }
        }
    }
    __syncthreads();

    // ---- exact reference rescore of candidates (parallel pass) ----
    {
        const int qn = s_qn;
        for (int i = tid; i < qn && i < QCAP; i += 256) {
            const unsigned e = s_q[i];
            const int row = e >> 16, code = e & 0xFFFF;
            const float* zr = &s_z[row * ZS];
            const float* er = emb + (size_t)code * 64;
            float a = 0.f, b = 0.f, c2 = 0.f, d = 0.f;
#pragma unroll
            for (int g = 0; g < 16; ++g) {
                a  += zr[4*g]   * er[4*g];   b += zr[4*g+1] * er[4*g+1];
                c2 += zr[4*g+2] * er[4*g+2]; d += zr[4*g+3] * er[4*g+3];
            }
            float dot  = (a + b) + (c2 + d);
            float dist = (s_zn2[row] + s_en2[code]) - 2.0f * dot;  // reference expr
            unsigned long long key =
                ((unsigned long long)__float_as_uint(dist) << 32) | (unsigned)code;
            atomicMin(&s_key[row], key);
        }
    }
    __syncthreads();

    // ---- epilogue: quantized_st, indices, loss (row = tid>>2, 16 floats) ----
    const int row = tid >> 2, seg = tid & 3;
    const int widx = (int)(unsigned)(s_key[row] & 0x1FFULL);
    const float* er = emb + (size_t)widx * 64 + seg * 16;
    const float* zr = &s_z[row * ZS + seg * 16];
    float* qo = out + 1 + ((size_t)blockIdx.x * ROWS + row) * 64 + seg * 16;
    float lsum = 0.f;
#pragma unroll
    for (int j = 0; j < 16; ++j) {
        float zv = zr[j], ev = er[j];
        float q = zv + (ev - zv);    // reference STE arithmetic
        float df = q - zv; lsum += df * df;
        qo[j] = q;
    }
    if (seg == 0)
        out[1 + NELEM + blockIdx.x * ROWS + row] = (float)widx;

#pragma unroll
    for (int off = 32; off; off >>= 1) lsum += __shfl_down(lsum, off, 64);
    if (lane == 0) s_lpart[wid] = lsum;
    __syncthreads();
    if (tid == 0) {
        float p = (s_lpart[0] + s_lpart[1]) + (s_lpart[2] + s_lpart[3]);
        atomicAdd(out, p * (1.25f / 8388608.0f));   // recon + 0.25*commit
    }
}

extern "C" void kernel_launch(void* const* d_in, const int* in_sizes, int n_in,
                              void* d_out, int out_size, void* d_ws, size_t ws_size,
                              hipStream_t stream) {
    const float* z   = (const float*)d_in[0];
    const float* emb = (const float*)d_in[1];
    float* out = (float*)d_out;

    vq_prep<<<17, 256, 0, stream>>>(emb, out);   // also zeroes out[0]
    vq_main<<<NBLK, 256, 0, stream>>>(z, emb, out);
}

// Round 8
// 131.251 us; speedup vs baseline: 1.3152x; 1.0982x over previous
//
#include <hip/hip_runtime.h>
#include <hip/hip_bf16.h>

// R12: wave-owns-CODES two-pass (R8 structure) + unroll cap 2 (R11 lesson).
// R11 post-mortem: wave-owns-rows made every wave stream the whole 64 KB
// E-table per pass (512 KB/block L2 reads); at ~8x16B in flight per lane and
// ~200cy L2 latency that stream is the floor (23.6 B/cyc/CU << 56 ceiling,
// all pipes idle). Wave-owns-codes cuts it 4x (each wave reads only its
// 16 KB slice per pass). R8 had this structure but spilled: its 8-iter ct
// loop was FULLY unrolled -> 128 e-regs live + 32 zf > 128 pinned budget.
// R11 proved the unroll cap controls live ranges; here unroll 2 -> ~95 regs.
// Numerics identical to R6-R11 (absmax 0.0): single-product bf16 scores
// (emb ~ U(+-1/512) -> score err std ~6e-5), EPS=1e-3 band, exact fp32
// reference rescore, u64 (dist_bits<<32|idx) atomicMin strict-< tie-break.
// Both passes use identical zf/e/base bits -> pass1 min == pass2 min exactly.
constexpr int NELEM = 8388608;            // 32*64*64*64
constexpr int ROWS  = 64;                 // rows per block
constexpr int NBLK  = 131072 / ROWS;      // 2048
constexpr int ZS    = 68;                 // fp32 z tile stride (dwords)
constexpr float EPS = 1e-3f;              // single-product band (R6-validated)
constexpr int QCAP  = 1024;               // candidate queue (~110 expected)

typedef short bf16x8 __attribute__((ext_vector_type(8)));
typedef float v4f    __attribute__((ext_vector_type(4)));

// Precomputed E fragments, hi-only, scale -2: [ct][kc][lane] -> 8 bf16, 64 KB.
__device__ bf16x8 g_efrag[32][2][64];
// Precomputed ||e||^2 in exact reference quad-accumulator order.
__device__ float  g_en2[512];

__device__ inline bf16x8 cvt_hi8(const float* __restrict__ s, float scale) {
    bf16x8 h;
#pragma unroll
    for (int j = 0; j < 8; ++j) {
        __hip_bfloat16 b = __float2bfloat16(scale * s[j]);
        h[j] = (short)__bfloat16_as_ushort(b);
    }
    return h;
}

// 17 blocks: 0..15 build E fragments (256 entries each), 16 builds en2 + out[0]=0.
__global__ void __launch_bounds__(256) vq_prep(const float* __restrict__ emb,
                                               float* __restrict__ out) {
    const int b = blockIdx.x;
    if (b < 16) {
        const int id   = b * 256 + threadIdx.x;   // (ct,kc,lane), 4096 total
        const int lane = id & 63;
        const int kc   = (id >> 6) & 1;
        const int ct   = id >> 7;
        const float* src = emb + (size_t)(ct * 16 + (lane & 15)) * 64
                               + kc * 32 + (lane >> 4) * 8;
        g_efrag[ct][kc][lane] = cvt_hi8(src, -2.0f);
    } else {
#pragma unroll
        for (int c = 0; c < 2; ++c) {
            const int k = threadIdx.x + c * 256;
            const float4* e4 = (const float4*)(emb + (size_t)k * 64);
            float a = 0.f, bq = 0.f, cc = 0.f, d = 0.f;
#pragma unroll
            for (int i = 0; i < 16; ++i) {
                float4 v = e4[i];
                a += v.x * v.x; bq += v.y * v.y; cc += v.z * v.z; d += v.w * v.w;
            }
            g_en2[k] = (a + bq) + (cc + d);
        }
        if (threadIdx.x == 0) out[0] = 0.f;
    }
}

// Block = 256 threads = 4 waves, 64 rows x 512 codes. Wave w owns codes
// [128w,128w+128) for ALL 64 rows (reads only its 16 KB E slice per pass).
// MFMA 16x16x32: A=-2E (m=code), B=Z (n=row), C: col=lane&15 (row),
// row-of-C=quad*4+reg (code) [m89 layout, R5-validated].
// Two-pass: pass1 -> per-row min (cross-wave LDS reduce), pass2 recompute +
// band scan. Z fragments zf[4][2] (32 VGPRs) computed once.
__global__ __launch_bounds__(256) __attribute__((amdgpu_waves_per_eu(4, 4)))
void vq_main(const float* __restrict__ z,
             const float* __restrict__ emb,
             float* __restrict__ out) {
    __shared__ float s_z[ROWS * ZS];          // 17.4 KB fp32 z tile
    __shared__ float s_en2[512];
    __shared__ float s_zn2[ROWS];
    __shared__ unsigned long long s_key[ROWS];
    __shared__ float s_wmin[ROWS][4];         // per-wave row mins
    __shared__ float s_thr[ROWS];             // global row min + EPS
    __shared__ unsigned s_q[QCAP];            // (row<<16)|code
    __shared__ int s_qn;
    __shared__ float s_lpart[4];

    const int tid  = threadIdx.x;
    const int lane = tid & 63;
    const int wid  = __builtin_amdgcn_readfirstlane(tid >> 6);
    const int mcol = lane & 15;
    const int quad = lane >> 4;

    // ---- stage z tile (coalesced), load en2, init queue/keys ----
    {
        const int row = tid >> 2, seg = tid & 3;
        const float4* gp = (const float4*)(z + ((size_t)blockIdx.x * ROWS + row) * 64 + seg * 16);
#pragma unroll
        for (int i = 0; i < 4; ++i)
            *(float4*)&s_z[row * ZS + seg * 16 + i * 4] = gp[i];
    }
    s_en2[tid]       = g_en2[tid];
    s_en2[tid + 256] = g_en2[tid + 256];
    if (tid < ROWS) s_key[tid] = ~0ULL;
    if (tid == 0) s_qn = 0;
    __syncthreads();

    // ---- exact zn2 per row, 4-way parallel with reference arithmetic:
    //      accumulator s sums z[4i+s] sequentially; combine (a+b)+(c+d).
    {
        const int row = tid >> 2, s = tid & 3;
        const float* zr = &s_z[row * ZS];
        float p = 0.f;
#pragma unroll
        for (int i = 0; i < 16; ++i) p += zr[4 * i + s] * zr[4 * i + s];
        p += __shfl_xor(p, 1, 64);   // a+b | c+d (fp add commutative: bit-exact)
        p += __shfl_xor(p, 2, 64);   // (a+b)+(c+d)
        if (s == 0) s_zn2[row] = p;
    }

    // ---- Z fragments (hi only) for all 4 row-groups: 32 VGPRs, cvt once ----
    bf16x8 zf[4][2];
#pragma unroll
    for (int rg = 0; rg < 4; ++rg) {
        zf[rg][0] = cvt_hi8(&s_z[(rg * 16 + mcol) * ZS +  0 + quad * 8], 1.0f);
        zf[rg][1] = cvt_hi8(&s_z[(rg * 16 + mcol) * ZS + 32 + quad * 8], 1.0f);
    }

    // ---- pass 1: row mins only (unroll 2: ~32 e-regs in flight) ----
    float lmin[4];
#pragma unroll
    for (int rg = 0; rg < 4; ++rg) lmin[rg] = 3.402823466e38f;
#pragma unroll 2
    for (int ct = 0; ct < 8; ++ct) {
        const int gct = wid * 8 + ct;
        bf16x8 e0 = g_efrag[gct][0][lane];
        bf16x8 e1 = g_efrag[gct][1][lane];
        v4f base = *(const v4f*)&s_en2[gct * 16 + quad * 4];  // broadcast read
#pragma unroll
        for (int rg = 0; rg < 4; ++rg) {
            v4f a = base;
            a = __builtin_amdgcn_mfma_f32_16x16x32_bf16(e0, zf[rg][0], a, 0, 0, 0);
            a = __builtin_amdgcn_mfma_f32_16x16x32_bf16(e1, zf[rg][1], a, 0, 0, 0);
            lmin[rg] = fminf(lmin[rg], fminf(fminf(a.x, a.y), fminf(a.z, a.w)));
        }
    }

    // ---- per-row min: reduce across quads, then across waves via LDS ----
#pragma unroll
    for (int rg = 0; rg < 4; ++rg) {
        float m = lmin[rg];
        m = fminf(m, __shfl_xor(m, 16, 64));
        m = fminf(m, __shfl_xor(m, 32, 64));
        if (quad == 0) s_wmin[rg * 16 + mcol][wid] = m;
    }
    __syncthreads();
    if (tid < ROWS)
        s_thr[tid] = fminf(fminf(s_wmin[tid][0], s_wmin[tid][1]),
                           fminf(s_wmin[tid][2], s_wmin[tid][3])) + EPS;
    __syncthreads();

    // ---- pass 2: recompute (identical bits -> deterministic), band scan ----
    float thr[4];
#pragma unroll
    for (int rg = 0; rg < 4; ++rg) thr[rg] = s_thr[rg * 16 + mcol];
#pragma unroll 2
    for (int ct = 0; ct < 8; ++ct) {
        const int gct = wid * 8 + ct;
        bf16x8 e0 = g_efrag[gct][0][lane];
        bf16x8 e1 = g_efrag[gct][1][lane];
        v4f base = *(const v4f*)&s_en2[gct * 16 + quad * 4];
#pragma unroll
        for (int rg = 0; rg < 4; ++rg) {
            v4f a = base;
            a = __builtin_amdgcn_mfma_f32_16x16x32_bf16(e0, zf[rg][0], a, 0, 0, 0);
            a = __builtin_amdgcn_mfma_f32_16x16x32_bf16(e1, zf[rg][1], a, 0, 0, 0);
            float m4 = fminf(fminf(a.x, a.y), fminf(a.z, a.w));
            if (m4 <= thr[rg]) {
#pragma unroll
                for (int r = 0; r < 4; ++r) {
                    if (a[r] <= thr[rg]) {
                        int slot = atomicAdd(&s_qn, 1);
                        if (slot < QCAP)
                            s_q[slot] = ((unsigned)(rg * 16 + mcol) << 16) |
                                        (unsigned)(wid * 128 + ct * 16 + quad * 4 + r);
                    }
                }
            }
        }
    }
    __syncthreads();

    // ---- exact reference rescore of candidates (parallel pass) ----
    {
        const int qn = s_qn;
        for (int i = tid; i < qn && i < QCAP; i += 256) {
            const unsigned e = s_q[i];
            const int row = e >> 16, code = e & 0xFFFF;
            const float* zr = &s_z[row * ZS];
            const float* er = emb + (size_t)code * 64;
            float a = 0.f, b = 0.f, c2 = 0.f, d = 0.f;
#pragma unroll
            for (int g = 0; g < 16; ++g) {
                a  += zr[4*g]   * er[4*g];   b += zr[4*g+1] * er[4*g+1];
                c2 += zr[4*g+2] * er[4*g+2]; d += zr[4*g+3] * er[4*g+3];
            }
            float dot  = (a + b) + (c2 + d);
            float dist = (s_zn2[row] + s_en2[code]) - 2.0f * dot;  // reference expr
            unsigned long long key =
                ((unsigned long long)__float_as_uint(dist) << 32) | (unsigned)code;
            atomicMin(&s_key[row], key);
        }
    }
    __syncthreads();

    // ---- epilogue: quantized_st, indices, loss (row = tid>>2, 16 floats) ----
    const int row = tid >> 2, seg = tid & 3;
    const int widx = (int)(unsigned)(s_key[row] & 0x1FFULL);
    const float* er = emb + (size_t)widx * 64 + seg * 16;
    const float* zr = &s_z[row * ZS + seg * 16];
    float* qo = out + 1 + ((size_t)blockIdx.x * ROWS + row) * 64 + seg * 16;
    float lsum = 0.f;
#pragma unroll
    for (int j = 0; j < 16; ++j) {
        float zv = zr[j], ev = er[j];
        float q = zv + (ev - zv);    // reference STE arithmetic
        float df = q - zv; lsum += df * df;
        qo[j] = q;
    }
    if (seg == 0)
        out[1 + NELEM + blockIdx.x * ROWS + row] = (float)widx;

#pragma unroll
    for (int off = 32; off; off >>= 1) lsum += __shfl_down(lsum, off, 64);
    if (lane == 0) s_lpart[wid] = lsum;
    __syncthreads();
    if (tid == 0) {
        float p = (s_lpart[0] + s_lpart[1]) + (s_lpart[2] + s_lpart[3]);
        atomicAdd(out, p * (1.25f / 8388608.0f));   // recon + 0.25*commit
    }
}

extern "C" void kernel_launch(void* const* d_in, const int* in_sizes, int n_in,
                              void* d_out, int out_size, void* d_ws, size_t ws_size,
                              hipStream_t stream) {
    const float* z   = (const float*)d_in[0];
    const float* emb = (const float*)d_in[1];
    float* out = (float*)d_out;

    vq_prep<<<17, 256, 0, stream>>>(emb, out);   // also zeroes out[0]
    vq_main<<<NBLK, 256, 0, stream>>>(z, emb, out);
}